// Round 9
// baseline (97.324 us; speedup 1.0000x reference)
//
#include <hip/hip_runtime.h>
#include <math.h>

#define BLOCK 256
#define LBv 1e-20f
#define UBv 1e20f

// Raw HW transcendentals: v_log_f32 / v_exp_f32 (~1 ulp).
// Edge semantics used deliberately: log2(0) = -inf, exp2(-inf) = 0 (c1>0).
#if __has_builtin(__builtin_amdgcn_logf) && __has_builtin(__builtin_amdgcn_exp2f)
__device__ __forceinline__ float fast_log2(float x) { return __builtin_amdgcn_logf(x); }
__device__ __forceinline__ float fast_exp2(float x) { return __builtin_amdgcn_exp2f(x); }
#else
__device__ __forceinline__ float fast_log2(float x) { return log2f(x); }
__device__ __forceinline__ float fast_exp2(float x) { return exp2f(x); }
#endif

// Epilogue + (cold) literal-reference fallback for one direction.
__device__ __forceinline__ void finish_dir(
    const float4* __restrict__ lv, int V, int tile, int d, int D,
    float dx, float dy, float dz, float pv, float c1,
    float S, float ax, float ay, float az,
    float mx, float my, float mz, float Sthresh,
    float* __restrict__ out, size_t offDH)
{
    size_t po  = ((size_t)tile * D + d) * 3;
    size_t dho = offDH + ((size_t)tile * D + d) * 4;

    if (S >= Sthresh) {
        // S >= V*1e-10  =>  zmax^p >= S/V >= 1e-10: no k-rescale, exponents
        // bounded (|log2 S| < 81), LB floors negligible, UB clip unreachable.
        float h = fminf(fmaxf(fast_exp2(fast_log2(S) * (1.f / pv)), LBv), UBv);
        float scale = fast_exp2(-c1 * fast_log2(h));   // h^-(p-1)
        out[po + 0] = fmaf(ax, scale, mx);
        out[po + 1] = fmaf(ay, scale, my);
        out[po + 2] = fmaf(az, scale, mz);
        out[dho + 0] = dx;
        out[dho + 1] = dy;
        out[dho + 2] = dz;
        out[dho + 3] = h;                               // k == 1
    } else {
        // ---- literal reference semantics (never taken for bench data) ----
        float zmax = 0.f;
        for (int v = 0; v < V; ++v) {
            float4 q = lv[v];
            float z = fmaf(q.x, dx, fmaf(q.y, dy, q.z * dz));
            zmax = fmaxf(zmax, z);
        }
        float zm_log   = (zmax > 0.f) ? log10f(zmax) : -INFINITY;
        float exponent = zm_log * pv;
        float lk = (exponent < -20.f) ? (-20.f - exponent) / pv : 0.f;
        float kk = powf(10.f, fminf(fmaxf(ceilf(lk), 0.f), UBv));

        float sum = 0.f;
        for (int v = 0; v < V; ++v) {
            float4 q = lv[v];
            float z   = fmaf(q.x, dx, fmaf(q.y, dy, q.z * dz));
            float zms = fmaxf(z, 0.f) * kk;
            float w   = (zms > 0.f) ? fminf(fmaxf(powf(zms, pv), LBv), UBv) : 0.f;
            sum += w;
        }
        float h = fminf(fmaxf(powf(sum, 1.f / pv), LBv), UBv);

        float bx = 0.f, by = 0.f, bz = 0.f;
        for (int v = 0; v < V; ++v) {
            float4 q = lv[v];
            float z     = fmaf(q.x, dx, fmaf(q.y, dy, q.z * dz));
            float zms   = fmaxf(z, 0.f) * kk;
            float ratio = zms / h;
            float w = (ratio > 0.f) ? fminf(fmaxf(powf(ratio, c1), LBv), UBv) : LBv;
            bx = fmaf(w, q.x, bx);
            by = fmaf(w, q.y, by);
            bz = fmaf(w, q.z, bz);
        }
        out[po + 0] = bx + mx;
        out[po + 1] = by + my;
        out[po + 2] = bz + mz;
        out[dho + 0] = dx;
        out[dho + 1] = dy;
        out[dho + 2] = dz;
        out[dho + 3] = h / kk;
    }
}

__global__ __launch_bounds__(BLOCK) void mcnet_fused2(
    const float* __restrict__ verts,   // (NT, V, 3) f32
    const float* __restrict__ smooth,  // (NT,)      f32
    const float* __restrict__ dirs,    // (D, 3)     f32
    float* __restrict__ out,           // f32, chunks concatenated flat
    int NT, int V, int D, int SPLIT,
    size_t offDH, size_t offMV, size_t offDIR, size_t offLV, size_t offZ)
{
    extern __shared__ float smem[];            // [4*V] lv (float4) + [3*BLOCK] reduce
    float4* lv = (float4*)smem;
    float*  red = smem + 4 * (size_t)V;

    const int tid  = threadIdx.x;
    const int tile = blockIdx.x / SPLIT;
    const int s    = blockIdx.x % SPLIT;

    // ---- mean via LDS tree reduction ----
    float sx = 0.f, sy = 0.f, sz = 0.f;
    for (int v = tid; v < V; v += BLOCK) {
        const float* vp = verts + ((size_t)tile * V + v) * 3;
        sx += vp[0]; sy += vp[1]; sz += vp[2];
    }
    red[tid] = sx; red[tid + BLOCK] = sy; red[tid + 2 * BLOCK] = sz;
    __syncthreads();
    for (int st = BLOCK / 2; st > 0; st >>= 1) {
        if (tid < st) {
            red[tid]             += red[tid + st];
            red[tid + BLOCK]     += red[tid + BLOCK + st];
            red[tid + 2 * BLOCK] += red[tid + 2 * BLOCK + st];
        }
        __syncthreads();
    }
    const float inv = 1.0f / (float)V;
    const float mx = red[0] * inv, my = red[BLOCK] * inv, mz = red[2 * BLOCK] * inv;

    for (int v = tid; v < V; v += BLOCK) {
        const float* vp = verts + ((size_t)tile * V + v) * 3;
        lv[v] = make_float4(vp[0] - mx, vp[1] - my, vp[2] - mz, 0.f);
    }
    __syncthreads();

    // ---- small outputs ----
    if (s == 0) {
        for (int v = tid; v < V; v += BLOCK) {
            float4 q = lv[v];
            size_t o = offLV + ((size_t)tile * V + v) * 3;
            out[o + 0] = q.x;
            out[o + 1] = q.y;
            out[o + 2] = q.z;
        }
        if (tid == 0) {
            size_t mo = offMV + (size_t)tile * 3;
            out[mo + 0] = mx;
            out[mo + 1] = my;
            out[mo + 2] = mz;
        }
    }
    if (blockIdx.x == 0) {
        for (int i = tid; i < D * 3; i += BLOCK)
            out[offDIR + i] = dirs[i];
        if (tid < 2) out[offZ + tid] = 0.f;
    }

    // ---- two directions per thread ----
    const int d0 = s * (2 * BLOCK) + tid;
    if (d0 >= D) return;
    const int d1 = d0 + BLOCK;
    const bool has1 = (d1 < D);
    const int d1c = has1 ? d1 : d0;        // clamp for safe loads

    const float dx0 = dirs[d0 * 3 + 0], dy0 = dirs[d0 * 3 + 1], dz0 = dirs[d0 * 3 + 2];
    const float dx1 = dirs[d1c * 3 + 0], dy1 = dirs[d1c * 3 + 1], dz1 = dirs[d1c * 3 + 2];
    const float pv = smooth[tile];
    const float c1 = pv - 1.f;
    const float Sthresh = (float)V * 1e-10f;

    float S0 = 0.f, ax0 = 0.f, ay0 = 0.f, az0 = 0.f;
    float S1 = 0.f, ax1 = 0.f, ay1 = 0.f, az1 = 0.f;

    #pragma unroll 4
    for (int v = 0; v < V; ++v) {
        float4 q = lv[v];
        float z0 = fmaf(q.x, dx0, fmaf(q.y, dy0, q.z * dz0));
        float z1 = fmaf(q.x, dx1, fmaf(q.y, dy1, q.z * dz1));
        float zc0 = fmaxf(z0, 0.f);
        float zc1 = fmaxf(z1, 0.f);
        float l0 = fast_log2(zc0);            // -inf at 0
        float l1 = fast_log2(zc1);
        float w0 = fast_exp2(c1 * l0);        // z^(p-1), 0 at z<=0
        float w1 = fast_exp2(c1 * l1);
        S0 = fmaf(w0, zc0, S0);               // z^p accumulated, no clip (see theory)
        S1 = fmaf(w1, zc1, S1);
        ax0 = fmaf(w0, q.x, ax0);
        ay0 = fmaf(w0, q.y, ay0);
        az0 = fmaf(w0, q.z, az0);
        ax1 = fmaf(w1, q.x, ax1);
        ay1 = fmaf(w1, q.y, ay1);
        az1 = fmaf(w1, q.z, az1);
    }

    finish_dir(lv, V, tile, d0, D, dx0, dy0, dz0, pv, c1,
               S0, ax0, ay0, az0, mx, my, mz, Sthresh, out, offDH);
    if (has1)
        finish_dir(lv, V, tile, d1, D, dx1, dy1, dz1, pv, c1,
                   S1, ax1, ay1, az1, mx, my, mz, Sthresh, out, offDH);
}

extern "C" void kernel_launch(void* const* d_in, const int* in_sizes, int n_in,
                              void* d_out, int out_size, void* d_ws, size_t ws_size,
                              hipStream_t stream) {
    const float* verts  = (const float*)d_in[0];
    const float* smooth = (const float*)d_in[1];
    const float* dirs   = (const float*)d_in[2];
    float* out = (float*)d_out;

    // verts = NT*V*3, smooth = NT, dirs = D*3
    const int NT = in_sizes[1];
    const int D  = in_sizes[2] / 3;
    const int V  = in_sizes[0] / (3 * NT);
    const int SPLIT = (D + 2 * BLOCK - 1) / (2 * BLOCK);   // 2 dirs per thread

    const size_t offDH  = (size_t)NT * D * 3;            // after points
    const size_t offMV  = offDH  + (size_t)NT * D * 4;   // after direction_h
    const size_t offDIR = offMV  + (size_t)NT * 3;       // after mean_v
    const size_t offLV  = offDIR + (size_t)D * 3;        // after directions
    const size_t offZ   = offLV  + (size_t)NT * V * 3;   // after local_vertices

    const size_t shmem = (4 * (size_t)V + 3 * BLOCK) * sizeof(float);

    dim3 grid(NT * SPLIT);
    dim3 block(BLOCK);
    hipLaunchKernelGGL(mcnet_fused2, grid, block, shmem, stream,
                       verts, smooth, dirs, out,
                       NT, V, D, SPLIT, offDH, offMV, offDIR, offLV, offZ);
}

// Round 10
// 91.800 us; speedup vs baseline: 1.0602x; 1.0602x over previous
//
#include <hip/hip_runtime.h>
#include <math.h>

#define BLOCK 256
#define LBv 1e-20f
#define UBv 1e20f

// Raw HW transcendentals: v_log_f32 / v_exp_f32 (~1 ulp).
// Edge semantics used deliberately: log2(0) = -inf, exp2(-inf) = 0 (c1>0).
#if __has_builtin(__builtin_amdgcn_logf) && __has_builtin(__builtin_amdgcn_exp2f)
__device__ __forceinline__ float fast_log2(float x) { return __builtin_amdgcn_logf(x); }
__device__ __forceinline__ float fast_exp2(float x) { return __builtin_amdgcn_exp2f(x); }
#else
__device__ __forceinline__ float fast_log2(float x) { return log2f(x); }
__device__ __forceinline__ float fast_exp2(float x) { return exp2f(x); }
#endif

__global__ __launch_bounds__(BLOCK) void mcnet_sreg(
    const float* __restrict__ verts,   // (NT, V, 3) f32
    const float* __restrict__ smooth,  // (NT,)      f32
    const float* __restrict__ dirs,    // (D, 3)     f32
    float* __restrict__ out,           // f32, chunks concatenated flat
    int NT, int V, int D, int SPLIT,
    size_t offDH, size_t offMV, size_t offDIR, size_t offLV, size_t offZ)
{
    __shared__ float red[3 * BLOCK];

    const int tid  = threadIdx.x;
    const int tile = blockIdx.x / SPLIT;
    const int s    = blockIdx.x % SPLIT;

    const float* vp0 = verts + (size_t)tile * V * 3;

    // ---- mean via LDS tree reduction ----
    float sx = 0.f, sy = 0.f, sz = 0.f;
    for (int v = tid; v < V; v += BLOCK) {
        sx += vp0[3 * v + 0]; sy += vp0[3 * v + 1]; sz += vp0[3 * v + 2];
    }
    red[tid] = sx; red[tid + BLOCK] = sy; red[tid + 2 * BLOCK] = sz;
    __syncthreads();
    for (int st = BLOCK / 2; st > 0; st >>= 1) {
        if (tid < st) {
            red[tid]             += red[tid + st];
            red[tid + BLOCK]     += red[tid + BLOCK + st];
            red[tid + 2 * BLOCK] += red[tid + 2 * BLOCK + st];
        }
        __syncthreads();
    }
    const float inv = 1.0f / (float)V;
    const float mx = red[0] * inv, my = red[BLOCK] * inv, mz = red[2 * BLOCK] * inv;

    // ---- small outputs ----
    if (s == 0) {
        for (int v = tid; v < V; v += BLOCK) {
            size_t o = offLV + ((size_t)tile * V + v) * 3;
            out[o + 0] = vp0[3 * v + 0] - mx;
            out[o + 1] = vp0[3 * v + 1] - my;
            out[o + 2] = vp0[3 * v + 2] - mz;
        }
        if (tid == 0) {
            size_t mo = offMV + (size_t)tile * 3;
            out[mo + 0] = mx;
            out[mo + 1] = my;
            out[mo + 2] = mz;
        }
    }
    if (blockIdx.x == 0) {
        for (int i = tid; i < D * 3; i += BLOCK)
            out[offDIR + i] = dirs[i];
        if (tid < 2) out[offZ + tid] = 0.f;
    }

    // ---- one direction per thread (max TLP: NT*SPLIT*4 waves) ----
    const int d = s * BLOCK + tid;
    if (d >= D) return;

    const float dx = dirs[d * 3 + 0];
    const float dy = dirs[d * 3 + 1];
    const float dz = dirs[d * 3 + 2];
    const float pv = smooth[tile];
    const float c1 = pv - 1.f;
    const float Sthresh = (float)V * 1e-10f;

    // z = v.d - m.d : read RAW verts (wave-uniform index -> s_load, no LDS),
    // accumulate unnormalized sums; mean-correct in the epilogue:
    //   sum w*lv = (sum w*v) - m*(sum w)
    const float nmd = -(mx * dx + my * dy + mz * dz);

    float S = 0.f, Wx = 0.f, Wy = 0.f, Wz = 0.f, Ws = 0.f;
    #pragma unroll 8
    for (int v = 0; v < V; ++v) {
        float vx = vp0[3 * v + 0];
        float vy = vp0[3 * v + 1];
        float vz = vp0[3 * v + 2];
        float z  = fmaf(vx, dx, fmaf(vy, dy, fmaf(vz, dz, nmd)));
        float zc = fmaxf(z, 0.f);
        float l  = fast_log2(zc);          // -inf at 0
        float w  = fast_exp2(c1 * l);      // z^(p-1), 0 at z<=0
        S  = fmaf(w, zc, S);               // z^p accumulated (no clip; see S-threshold)
        Wx = fmaf(w, vx, Wx);
        Wy = fmaf(w, vy, Wy);
        Wz = fmaf(w, vz, Wz);
        Ws += w;
    }

    size_t po  = ((size_t)tile * D + d) * 3;
    size_t dho = offDH + ((size_t)tile * D + d) * 4;

    if (S >= Sthresh) {
        // S >= V*1e-10 => zmax^p >= 1e-10: no k-rescale, exponents bounded,
        // LB floors negligible, UB clip unreachable.
        float h = fminf(fmaxf(fast_exp2(fast_log2(S) * (1.f / pv)), LBv), UBv);
        float scale = fast_exp2(-c1 * fast_log2(h));   // h^-(p-1)
        float ax = fmaf(-mx, Ws, Wx);                  // sum w*lv
        float ay = fmaf(-my, Ws, Wy);
        float az = fmaf(-mz, Ws, Wz);
        out[po + 0] = fmaf(ax, scale, mx);
        out[po + 1] = fmaf(ay, scale, my);
        out[po + 2] = fmaf(az, scale, mz);
        out[dho + 0] = dx;
        out[dho + 1] = dy;
        out[dho + 2] = dz;
        out[dho + 3] = h;                               // k == 1
    } else {
        // ---- literal reference semantics (cold; never taken for bench data) ----
        float zmax = 0.f;
        for (int v = 0; v < V; ++v) {
            float z = fmaf(vp0[3 * v] - mx, dx,
                      fmaf(vp0[3 * v + 1] - my, dy, (vp0[3 * v + 2] - mz) * dz));
            zmax = fmaxf(zmax, z);
        }
        float zm_log   = (zmax > 0.f) ? log10f(zmax) : -INFINITY;
        float exponent = zm_log * pv;
        float lk = (exponent < -20.f) ? (-20.f - exponent) / pv : 0.f;
        float kk = powf(10.f, fminf(fmaxf(ceilf(lk), 0.f), UBv));

        float sum = 0.f;
        for (int v = 0; v < V; ++v) {
            float z = fmaf(vp0[3 * v] - mx, dx,
                      fmaf(vp0[3 * v + 1] - my, dy, (vp0[3 * v + 2] - mz) * dz));
            float zms = fmaxf(z, 0.f) * kk;
            float w   = (zms > 0.f) ? fminf(fmaxf(powf(zms, pv), LBv), UBv) : 0.f;
            sum += w;
        }
        float h = fminf(fmaxf(powf(sum, 1.f / pv), LBv), UBv);

        float bx = 0.f, by = 0.f, bz = 0.f;
        for (int v = 0; v < V; ++v) {
            float lx = vp0[3 * v] - mx, ly = vp0[3 * v + 1] - my, lz = vp0[3 * v + 2] - mz;
            float z     = fmaf(lx, dx, fmaf(ly, dy, lz * dz));
            float zms   = fmaxf(z, 0.f) * kk;
            float ratio = zms / h;
            float w = (ratio > 0.f) ? fminf(fmaxf(powf(ratio, c1), LBv), UBv) : LBv;
            bx = fmaf(w, lx, bx);
            by = fmaf(w, ly, by);
            bz = fmaf(w, lz, bz);
        }
        out[po + 0] = bx + mx;
        out[po + 1] = by + my;
        out[po + 2] = bz + mz;
        out[dho + 0] = dx;
        out[dho + 1] = dy;
        out[dho + 2] = dz;
        out[dho + 3] = h / kk;
    }
}

extern "C" void kernel_launch(void* const* d_in, const int* in_sizes, int n_in,
                              void* d_out, int out_size, void* d_ws, size_t ws_size,
                              hipStream_t stream) {
    const float* verts  = (const float*)d_in[0];
    const float* smooth = (const float*)d_in[1];
    const float* dirs   = (const float*)d_in[2];
    float* out = (float*)d_out;

    // verts = NT*V*3, smooth = NT, dirs = D*3
    const int NT = in_sizes[1];
    const int D  = in_sizes[2] / 3;
    const int V  = in_sizes[0] / (3 * NT);
    const int SPLIT = (D + BLOCK - 1) / BLOCK;           // 1 dir per thread

    const size_t offDH  = (size_t)NT * D * 3;            // after points
    const size_t offMV  = offDH  + (size_t)NT * D * 4;   // after direction_h
    const size_t offDIR = offMV  + (size_t)NT * 3;       // after mean_v
    const size_t offLV  = offDIR + (size_t)D * 3;        // after directions
    const size_t offZ   = offLV  + (size_t)NT * V * 3;   // after local_vertices

    dim3 grid(NT * SPLIT);
    dim3 block(BLOCK);
    hipLaunchKernelGGL(mcnet_sreg, grid, block, 0, stream,
                       verts, smooth, dirs, out,
                       NT, V, D, SPLIT, offDH, offMV, offDIR, offLV, offZ);
}